// Round 1
// baseline (715.574 us; speedup 1.0000x reference)
//
#include <hip/hip_runtime.h>
#include <hip/hip_bf16.h>
#include <cstdint>
#include <cstddef>

// Problem constants (from reference)
#define B_  8192
#define T_  96
#define K_  32
#define H_  768
#define NK_ (T_ * K_)   // 3072

// ---------------------------------------------------------------------------
// Kernel 1: em = sigmoid(hidden @ W + bias), em stored [B, T*K] f32 in ws.
// Classic fp32 SGEMM: 128x128 tile, 256 threads, 8x8 per thread, BK=8.
// ---------------------------------------------------------------------------
__global__ __launch_bounds__(256) void gemm_sigmoid_kernel(
    const float* __restrict__ A,     // [B_, H_]
    const float* __restrict__ W,     // [H_, NK_]
    const float* __restrict__ bias,  // [NK_]
    float* __restrict__ em)          // [B_, NK_]
{
    __shared__ float As[8][128];   // transposed A tile: As[k][m]
    __shared__ float Bs[8][128];   // Bs[k][n]

    const int tid  = threadIdx.x;
    const int bn   = blockIdx.x;   // 0..23
    const int bm   = blockIdx.y;   // 0..63
    const int row0 = bm * 128;
    const int col0 = bn * 128;
    const int tm   = tid >> 4;     // 0..15
    const int tn   = tid & 15;     // 0..15

    // global load assignments
    const int aRow = tid >> 1;          // 0..127
    const int aCol = (tid & 1) * 4;     // 0 or 4
    const int bRow = tid >> 5;          // 0..7
    const int bCol = (tid & 31) * 4;    // 0..124

    float acc[8][8];
#pragma unroll
    for (int i = 0; i < 8; i++)
#pragma unroll
        for (int j = 0; j < 8; j++) acc[i][j] = 0.0f;

    for (int k0 = 0; k0 < H_; k0 += 8) {
        // issue global loads before the barrier (prefetch overlap)
        float4 av = *(const float4*)(A + (size_t)(row0 + aRow) * H_ + k0 + aCol);
        float4 bv = *(const float4*)(W + (size_t)(k0 + bRow) * NK_ + col0 + bCol);
        __syncthreads();   // everyone done reading previous tile
        As[aCol + 0][aRow] = av.x;
        As[aCol + 1][aRow] = av.y;
        As[aCol + 2][aRow] = av.z;
        As[aCol + 3][aRow] = av.w;
        *(float4*)&Bs[bRow][bCol] = bv;
        __syncthreads();
#pragma unroll
        for (int kk = 0; kk < 8; kk++) {
            float4 a0 = *(const float4*)&As[kk][tm * 8];
            float4 a1 = *(const float4*)&As[kk][tm * 8 + 4];
            float4 b0 = *(const float4*)&Bs[kk][tn * 8];
            float4 b1 = *(const float4*)&Bs[kk][tn * 8 + 4];
            float a[8] = {a0.x, a0.y, a0.z, a0.w, a1.x, a1.y, a1.z, a1.w};
            float bb[8] = {b0.x, b0.y, b0.z, b0.w, b1.x, b1.y, b1.z, b1.w};
#pragma unroll
            for (int i = 0; i < 8; i++)
#pragma unroll
                for (int j = 0; j < 8; j++) acc[i][j] = fmaf(a[i], bb[j], acc[i][j]);
        }
    }

    // epilogue: bias + sigmoid, vectorized store
#pragma unroll
    for (int i = 0; i < 8; i++) {
        const int r = row0 + tm * 8 + i;
#pragma unroll
        for (int j = 0; j < 8; j += 4) {
            const int c = col0 + tn * 8 + j;
            float4 o;
            float x0 = acc[i][j + 0] + bias[c + 0];
            float x1 = acc[i][j + 1] + bias[c + 1];
            float x2 = acc[i][j + 2] + bias[c + 2];
            float x3 = acc[i][j + 3] + bias[c + 3];
            o.x = 1.0f / (1.0f + __expf(-x0));
            o.y = 1.0f / (1.0f + __expf(-x1));
            o.z = 1.0f / (1.0f + __expf(-x2));
            o.w = 1.0f / (1.0f + __expf(-x3));
            *(float4*)(em + (size_t)r * NK_ + c) = o;
        }
    }
}

// ---------------------------------------------------------------------------
// Kernel 2: fused CRF forward. One 32-lane group per sequence b.
// Lane k holds alpha[b,k] (logsumexp recurrence) and v[b,k] (Viterbi).
// Transitions column trans[:,k] kept in 32 registers per lane.
// alpha/v exchanged via per-group LDS (half-wave private: no barriers).
// Also accumulates gold-path unary+binary score.
// Outputs: bps (backpointers u8), last_tag, ll = score - logZ.
// ---------------------------------------------------------------------------
__global__ __launch_bounds__(256) void crf_scan_kernel(
    const float* __restrict__ em,       // [B_, NK_]
    const int* __restrict__ target,     // [B_, T_]
    const float* __restrict__ trans,    // [K_, K_]
    unsigned char* __restrict__ bps,    // [T_-1, B_, K_]
    int* __restrict__ last_tag,         // [B_]
    float* __restrict__ ll)             // [B_]
{
    __shared__ float  trans_s[K_ * K_];     // 4 KB
    __shared__ float2 av_s[8][K_];          // 2 KB, per-group alpha/v exchange

    const int tid = threadIdx.x;
    const int g   = tid >> 5;    // group in block (0..7)
    const int k   = tid & 31;    // tag index = lane within group
    const int b   = blockIdx.x * 8 + g;

    for (int i = tid; i < K_ * K_; i += 256) trans_s[i] = trans[i];
    __syncthreads();

    // tcol[p] = trans[p][k]  (column of transitions for this next-tag)
    float tcol[K_];
#pragma unroll
    for (int p = 0; p < K_; p++) tcol[p] = trans_s[p * K_ + k];

    const float* emb = em + (size_t)b * NK_;

    const float em0 = emb[k];
    float alpha = em0;
    float v     = em0;
    int   tgt_prev = target[b * T_];
    float unary  = (k == tgt_prev) ? em0 : 0.0f;
    float binary = 0.0f;

    for (int t = 1; t < T_; t++) {
        const float em_t = emb[t * K_ + k];

        av_s[g][k] = make_float2(alpha, v);
        __builtin_amdgcn_wave_barrier();   // keep LDS write/read ordering

        float sa[K_];
        float m  = -1e30f;
        float bv = -1e30f;
        int   bi = 0;
#pragma unroll
        for (int p = 0; p < K_; p++) {
            float2 x = av_s[g][p];         // broadcast read
            sa[p] = x.x + tcol[p];
            m = fmaxf(m, sa[p]);
            float sv = x.y + tcol[p];
            if (sv > bv) { bv = sv; bi = p; }   // first-max on ties (p ascending)
        }
        float sum = 0.0f;
#pragma unroll
        for (int p = 0; p < K_; p++) sum += __expf(sa[p] - m);

        alpha = m + __logf(sum) + em_t;
        v     = bv + em_t;
        bps[(size_t)(t - 1) * (B_ * K_) + (size_t)b * K_ + k] = (unsigned char)bi;

        const int tgt = target[b * T_ + t];
        unary  += (k == tgt) ? em_t : 0.0f;
        binary += trans_s[tgt_prev * K_ + tgt];   // same addr in group: broadcast
        tgt_prev = tgt;
    }

    // ---- reductions across the 32-lane group ----
    // logZ = logsumexp_k(alpha)
    float m2 = alpha;
#pragma unroll
    for (int d = 16; d >= 1; d >>= 1) m2 = fmaxf(m2, __shfl_xor(m2, d));
    float s2 = __expf(alpha - m2);
#pragma unroll
    for (int d = 16; d >= 1; d >>= 1) s2 += __shfl_xor(s2, d);
    const float logZ = m2 + __logf(s2);

    // unary sum across lanes
    float un = unary;
#pragma unroll
    for (int d = 16; d >= 1; d >>= 1) un += __shfl_xor(un, d);

    // argmax_k(v) with first-index tie-break
    float bvv = v;
    int   bii = k;
#pragma unroll
    for (int d = 16; d >= 1; d >>= 1) {
        float ov = __shfl_xor(bvv, d);
        int   oi = __shfl_xor(bii, d);
        if (ov > bvv || (ov == bvv && oi < bii)) { bvv = ov; bii = oi; }
    }

    if (k == 0) {
        ll[b]       = un + binary - logZ;
        last_tag[b] = bii;
    }
}

// ---------------------------------------------------------------------------
// Kernel 3: Viterbi backtrace. One thread per sequence.
// Output tag at index t follows the reference layout tags[b][t], written as f32.
// ---------------------------------------------------------------------------
__global__ __launch_bounds__(256) void backtrace_kernel(
    const unsigned char* __restrict__ bps,  // [T_-1, B_, K_]
    const int* __restrict__ last_tag,       // [B_]
    float* __restrict__ out_tags)           // [B_, T_] as f32 values
{
    const int b = blockIdx.x * 256 + threadIdx.x;
    if (b >= B_) return;
    int tag = last_tag[b];
    out_tags[(size_t)b * T_ + (T_ - 1)] = (float)tag;
    for (int t = T_ - 2; t >= 0; t--) {
        tag = bps[(size_t)t * (B_ * K_) + (size_t)b * K_ + tag];
        out_tags[(size_t)b * T_ + t] = (float)tag;
    }
}

// ---------------------------------------------------------------------------
extern "C" void kernel_launch(void* const* d_in, const int* in_sizes, int n_in,
                              void* d_out, int out_size, void* d_ws, size_t ws_size,
                              hipStream_t stream)
{
    const float* hidden = (const float*)d_in[0];   // [B_, H_]
    const int*   target = (const int*)d_in[1];     // [B_, T_]
    const float* W      = (const float*)d_in[2];   // [H_, NK_]
    const float* bias   = (const float*)d_in[3];   // [NK_]
    const float* trans  = (const float*)d_in[4];   // [K_, K_]

    float* out      = (float*)d_out;
    float* out_tags = out;                       // B_*T_ elements (tags as f32)
    float* out_ll   = out + (size_t)B_ * T_;     // B_ elements

    char* ws = (char*)d_ws;
    float*         em   = (float*)ws;                                  // 100.7 MB
    unsigned char* bps  = (unsigned char*)(ws + (size_t)B_ * NK_ * 4); // 24.9 MB
    int* last_tag = (int*)(ws + (size_t)B_ * NK_ * 4 + (size_t)(T_ - 1) * B_ * K_);

    dim3 gemm_grid(NK_ / 128, B_ / 128);  // (24, 64)
    gemm_sigmoid_kernel<<<gemm_grid, 256, 0, stream>>>(hidden, W, bias, em);

    crf_scan_kernel<<<B_ / 8, 256, 0, stream>>>(em, target, trans, bps, last_tag, out_ll);

    backtrace_kernel<<<B_ / 256, 256, 0, stream>>>(bps, last_tag, out_tags);
}

// Round 3
// 300.834 us; speedup vs baseline: 2.3786x; 2.3786x over previous
//
#include <hip/hip_runtime.h>
#include <cstdint>
#include <cstddef>

// Problem constants
#define B_  8192
#define T_  96
#define K_  32
#define H_  768
#define NK_ (T_ * K_)   // 3072

typedef __attribute__((ext_vector_type(8))) _Float16 f16x8;
typedef __attribute__((ext_vector_type(4))) float    f32x4;

#define SCALE_UP   4096.0f            // 2^12 on A and W each
#define SCALE_DOWN (1.0f / 16777216.0f)  // 2^-24

__device__ __forceinline__ void load_lds16(const void* g, void* l) {
    __builtin_amdgcn_global_load_lds(
        (const __attribute__((address_space(1))) unsigned int*)g,
        (__attribute__((address_space(3))) unsigned int*)l,
        16, 0, 0);
}

// ---------------------------------------------------------------------------
// Prepass A: split A*4096 into fp16 hi/lo, stored in GEMM-tile-ready layout:
// tile (rb, ks) of 128 rows x 32 k = 4096 halfs at (rb*24+ks)*4096; within:
// row r, k-quarter q (8 halfs): offset r*32 + ((q ^ ((r>>1)&3)) << 3).
// ---------------------------------------------------------------------------
__global__ __launch_bounds__(256) void splitA_kernel(
    const float* __restrict__ A, _Float16* __restrict__ Ath, _Float16* __restrict__ Atl)
{
    const int g   = blockIdx.x * 256 + threadIdx.x;   // 8192*96 total
    const int row = g / 96;
    const int o   = g - row * 96;      // k-octet 0..95
    const int ks  = o >> 2, qq = o & 3;
    const int r   = row & 127, rb = row >> 7;
    const size_t dst = (size_t)(rb * 24 + ks) * 4096 + r * 32 + ((qq ^ ((r >> 1) & 3)) << 3);

    f32x4 v0 = *(const f32x4*)(A + (size_t)row * H_ + o * 8);
    f32x4 v1 = *(const f32x4*)(A + (size_t)row * H_ + o * 8 + 4);
    f16x8 hi, lo;
#pragma unroll
    for (int e = 0; e < 8; e++) {
        float x = ((e < 4) ? v0[e] : v1[e - 4]) * SCALE_UP;
        _Float16 h = (_Float16)x;
        hi[e] = h;
        lo[e] = (_Float16)(x - (float)h);
    }
    *(f16x8*)&Ath[dst] = hi;
    *(f16x8*)&Atl[dst] = lo;
}

// ---------------------------------------------------------------------------
// Prepass W: same split for W*4096, tiles (cb, ks): col n, k-quarter q at
// (cb*24+ks)*4096 + n*32 + ((q ^ ((n>>1)&3)) << 3).  (k-strided loads,
// coalesced across lanes since col varies fastest.)
// ---------------------------------------------------------------------------
__global__ __launch_bounds__(256) void splitW_kernel(
    const float* __restrict__ W, _Float16* __restrict__ Wth, _Float16* __restrict__ Wtl)
{
    const int g   = blockIdx.x * 256 + threadIdx.x;   // 3072*96 total
    const int ko  = g / NK_;            // k-octet 0..95
    const int col = g - ko * NK_;
    const int k0  = ko * 8;
    const int cb  = col >> 7, n = col & 127;
    const int ks  = k0 >> 5, qq = (k0 & 31) >> 3;
    const size_t dst = (size_t)(cb * 24 + ks) * 4096 + n * 32 + ((qq ^ ((n >> 1) & 3)) << 3);

    f16x8 hi, lo;
#pragma unroll
    for (int j = 0; j < 8; j++) {
        float x = W[(size_t)(k0 + j) * NK_ + col] * SCALE_UP;
        _Float16 h = (_Float16)x;
        hi[j] = h;
        lo[j] = (_Float16)(x - (float)h);
    }
    *(f16x8*)&Wth[dst] = hi;
    *(f16x8*)&Wtl[dst] = lo;
}

// ---------------------------------------------------------------------------
// GEMM: em = sigmoid((Ah+Al)@(Wh+Wl)*2^-24 + bias) via fp16 MFMA, 3 terms
// (hh, hl, lh). 128x128 tile, BK=32, 4 waves (2x2), 4x4 frags/wave,
// double-buffered LDS filled by global_load_lds dwordx4 (pre-swizzled src).
// ---------------------------------------------------------------------------
__global__ __launch_bounds__(256, 2) void gemm_mfma_sigmoid_kernel(
    const _Float16* __restrict__ Ath, const _Float16* __restrict__ Atl,
    const _Float16* __restrict__ Wth, const _Float16* __restrict__ Wtl,
    const float* __restrict__ bias, float* __restrict__ em)
{
    __shared__ _Float16 lds[2][4][4096];   // [buf][Ah,Al,Bh,Bl][tile]  = 64 KB

    const int tid  = threadIdx.x;
    const int cb   = blockIdx.x;           // 0..23
    const int rb   = blockIdx.y;           // 0..63
    const int lane = tid & 63;
    const int w    = tid >> 6;
    const int wr   = w >> 1, wc = w & 1;
    const int fr   = lane & 15;
    const int kg   = lane >> 4;

    const _Float16* srcs[4] = {
        Ath + (size_t)(rb * 24) * 4096, Atl + (size_t)(rb * 24) * 4096,
        Wth + (size_t)(cb * 24) * 4096, Wtl + (size_t)(cb * 24) * 4096 };

    auto stage = [&](int ks, int bb) {
#pragma unroll
        for (int m = 0; m < 4; m++) {
            const _Float16* s = srcs[m] + (size_t)ks * 4096 + w * 1024 + lane * 8;
            _Float16* d = &lds[bb][m][w * 1024];
            load_lds16(s, d);
            load_lds16(s + 512, d + 512);
        }
    };

    f32x4 acc[4][4];
#pragma unroll
    for (int i = 0; i < 4; i++)
#pragma unroll
        for (int j = 0; j < 4; j++) acc[i][j] = (f32x4)0.0f;

    int cur = 0;
    stage(0, 0);

    for (int ks = 0; ks < 24; ks++) {
        __syncthreads();                       // vmcnt drained: buf[cur] ready
        if (ks + 1 < 24) stage(ks + 1, cur ^ 1);

        f16x8 fah[4], fal[4], fbh[4], fbl[4];
#pragma unroll
        for (int mi = 0; mi < 4; mi++) {
            const int r   = wr * 64 + mi * 16 + fr;
            const int idx = r * 32 + ((kg ^ ((r >> 1) & 3)) << 3);
            fah[mi] = *(const f16x8*)&lds[cur][0][idx];
            fal[mi] = *(const f16x8*)&lds[cur][1][idx];
        }
#pragma unroll
        for (int ni = 0; ni < 4; ni++) {
            const int r   = wc * 64 + ni * 16 + fr;
            const int idx = r * 32 + ((kg ^ ((r >> 1) & 3)) << 3);
            fbh[ni] = *(const f16x8*)&lds[cur][2][idx];
            fbl[ni] = *(const f16x8*)&lds[cur][3][idx];
        }
#pragma unroll
        for (int mi = 0; mi < 4; mi++)
#pragma unroll
            for (int ni = 0; ni < 4; ni++) {
                acc[mi][ni] = __builtin_amdgcn_mfma_f32_16x16x32_f16(fah[mi], fbh[ni], acc[mi][ni], 0, 0, 0);
                acc[mi][ni] = __builtin_amdgcn_mfma_f32_16x16x32_f16(fah[mi], fbl[ni], acc[mi][ni], 0, 0, 0);
                acc[mi][ni] = __builtin_amdgcn_mfma_f32_16x16x32_f16(fal[mi], fbh[ni], acc[mi][ni], 0, 0, 0);
            }
        cur ^= 1;
    }

    // epilogue: unscale + bias + sigmoid. C/D: col=lane&15, row=(lane>>4)*4+reg
    const int er = rb * 128 + wr * 64 + (lane >> 4) * 4;
    const int ec = cb * 128 + wc * 64 + fr;
#pragma unroll
    for (int ni = 0; ni < 4; ni++) {
        const int   gc = ec + ni * 16;
        const float bv = bias[gc];
#pragma unroll
        for (int mi = 0; mi < 4; mi++)
#pragma unroll
            for (int r = 0; r < 4; r++) {
                const int gr = er + mi * 16 + r;
                float x = acc[mi][ni][r] * SCALE_DOWN + bv;
                em[(size_t)gr * NK_ + gc] = 1.0f / (1.0f + __expf(-x));
            }
    }
}

// ---------------------------------------------------------------------------
// CRF forward + fused backtrace. One 32-lane group per sequence.
// logsumexp via exp-space: Ecol = exp(tcol) in regs; per step one group-max,
// one exp, 32 FMA. Viterbi arithmetic identical to the R1-passing version.
// Backpointers packed 4-per-u32 in LDS; lane 0 backtraces at the end.
// ---------------------------------------------------------------------------
__global__ __launch_bounds__(256) void crf_scan_kernel(
    const float* __restrict__ em,       // [B_, NK_]
    const int* __restrict__ target,     // [B_, T_]
    const float* __restrict__ trans,    // [K_, K_]
    float* __restrict__ out_tags,       // [B_, T_] as f32
    float* __restrict__ ll)             // [B_]
{
    __shared__ float  trans_s[K_ * K_];          // 4 KB
    __shared__ float4 ev4[8][16];                // (e,v) pairs, 2 KB
    __shared__ unsigned int bp_s[8][24][K_];     // packed bps, 24 KB

    const int tid = threadIdx.x;
    const int g   = tid >> 5;
    const int k   = tid & 31;
    const int b   = blockIdx.x * 8 + g;

    for (int i = tid; i < K_ * K_; i += 256) trans_s[i] = trans[i];
    __syncthreads();

    float tcol[K_], Ecol[K_];
#pragma unroll
    for (int p = 0; p < K_; p++) {
        tcol[p] = trans_s[p * K_ + k];
        Ecol[p] = __expf(tcol[p]);
    }

    const float* emb = em + (size_t)b * NK_;

    const float em0 = emb[k];
    float alpha = em0;
    float v     = em0;
    int   tgt_prev = target[b * T_];
    float unary  = (k == tgt_prev) ? em0 : 0.0f;
    float binary = 0.0f;
    unsigned int bpw = 0;

    float2* evp = (float2*)&ev4[g][0];

    for (int t = 1; t < T_; t++) {
        const float em_t = emb[t * K_ + k];

        // group max of alpha (exact logsumexp shift)
        float mh = alpha;
#pragma unroll
        for (int d = 16; d >= 1; d >>= 1) mh = fmaxf(mh, __shfl_xor(mh, d));
        const float e = __expf(alpha - mh);

        evp[k] = make_float2(e, v);
        __builtin_amdgcn_wave_barrier();

        float sum = 0.0f;
        float bv  = -1e30f;
        int   bi  = 0;
#pragma unroll
        for (int c = 0; c < 16; c++) {
            f32x4 q = *(const f32x4*)&ev4[g][c];
            const int p0 = 2 * c, p1 = 2 * c + 1;
            sum = fmaf(q[0], Ecol[p0], sum);
            float sv0 = q[1] + tcol[p0];
            if (sv0 > bv) { bv = sv0; bi = p0; }
            sum = fmaf(q[2], Ecol[p1], sum);
            float sv1 = q[3] + tcol[p1];
            if (sv1 > bv) { bv = sv1; bi = p1; }
        }

        alpha = mh + __logf(sum) + em_t;
        v     = bv + em_t;

        bpw |= (unsigned int)bi << (8 * ((t - 1) & 3));
        if (((t - 1) & 3) == 3) { bp_s[g][(t - 1) >> 2][k] = bpw; bpw = 0; }

        const int tgt = target[b * T_ + t];
        unary  += (k == tgt) ? em_t : 0.0f;
        binary += trans_s[tgt_prev * K_ + tgt];
        tgt_prev = tgt;
    }
    bp_s[g][23][k] = bpw;   // partial word (t=93..95)
    __builtin_amdgcn_wave_barrier();

    // ---- group reductions ----
    float m2 = alpha;
#pragma unroll
    for (int d = 16; d >= 1; d >>= 1) m2 = fmaxf(m2, __shfl_xor(m2, d));
    float s2 = __expf(alpha - m2);
#pragma unroll
    for (int d = 16; d >= 1; d >>= 1) s2 += __shfl_xor(s2, d);
    const float logZ = m2 + __logf(s2);

    float un = unary;
#pragma unroll
    for (int d = 16; d >= 1; d >>= 1) un += __shfl_xor(un, d);

    float bvv = v;
    int   bii = k;
#pragma unroll
    for (int d = 16; d >= 1; d >>= 1) {
        float ov = __shfl_xor(bvv, d);
        int   oi = __shfl_xor(bii, d);
        if (ov > bvv || (ov == bvv && oi < bii)) { bvv = ov; bii = oi; }
    }

    if (k == 0) {
        ll[b] = un + binary - logZ;
        // fused backtrace
        float* ot = out_tags + (size_t)b * T_;
        int tag = bii;
        ot[T_ - 1] = (float)tag;
        for (int t = T_ - 2; t >= 0; t--) {
            unsigned int wd = bp_s[g][t >> 2][tag];
            tag = (wd >> (8 * (t & 3))) & 0xFF;
            ot[t] = (float)tag;
        }
    }
}

// ---------------------------------------------------------------------------
extern "C" void kernel_launch(void* const* d_in, const int* in_sizes, int n_in,
                              void* d_out, int out_size, void* d_ws, size_t ws_size,
                              hipStream_t stream)
{
    const float* hidden = (const float*)d_in[0];
    const int*   target = (const int*)d_in[1];
    const float* W      = (const float*)d_in[2];
    const float* bias   = (const float*)d_in[3];
    const float* trans  = (const float*)d_in[4];

    float* out      = (float*)d_out;
    float* out_tags = out;                    // B_*T_ tags (as f32)
    float* out_ll   = out + (size_t)B_ * T_;  // B_ log-likelihoods

    char* ws = (char*)d_ws;
    const size_t emB = (size_t)B_ * NK_ * 4;   // 100.66 MB
    const size_t ahB = (size_t)B_ * H_ * 2;    // 12.58 MB
    const size_t whB = (size_t)H_ * NK_ * 2;   // 4.72 MB
    float*    em  = (float*)ws;
    _Float16* Ath = (_Float16*)(ws + emB);
    _Float16* Atl = (_Float16*)(ws + emB + ahB);
    _Float16* Wth = (_Float16*)(ws + emB + 2 * ahB);
    _Float16* Wtl = (_Float16*)(ws + emB + 2 * ahB + whB);

    splitA_kernel<<<(B_ * 96) / 256, 256, 0, stream>>>(hidden, Ath, Atl);
    splitW_kernel<<<(NK_ * 96) / 256, 256, 0, stream>>>(W, Wth, Wtl);

    dim3 gemm_grid(NK_ / 128, B_ / 128);  // (24, 64)
    gemm_mfma_sigmoid_kernel<<<gemm_grid, 256, 0, stream>>>(Ath, Atl, Wth, Wtl, bias, em);

    crf_scan_kernel<<<B_ / 8, 256, 0, stream>>>(em, target, trans, out_tags, out_ll);
}

// Round 4
// 271.875 us; speedup vs baseline: 2.6320x; 1.1065x over previous
//
#include <hip/hip_runtime.h>
#include <cstdint>
#include <cstddef>

// Problem constants
#define B_  8192
#define T_  96
#define K_  32
#define H_  768
#define NK_ (T_ * K_)   // 3072

typedef __attribute__((ext_vector_type(8))) _Float16 f16x8;
typedef __attribute__((ext_vector_type(4))) float    f32x4;
typedef __attribute__((ext_vector_type(2))) float    f32x2;

#define SCALE_UP   4096.0f               // 2^12 on A and W each
#define SCALE_DOWN (1.0f / 16777216.0f)  // 2^-24

__device__ __forceinline__ void load_lds16(const void* g, void* l) {
    __builtin_amdgcn_global_load_lds(
        (const __attribute__((address_space(1))) unsigned int*)g,
        (__attribute__((address_space(3))) unsigned int*)l,
        16, 0, 0);
}

// Packed fp32 ops (full-rate VOP3P on CDNA4): 2 f32 ops per instruction.
__device__ __forceinline__ f32x2 pk_add(f32x2 a, f32x2 b) {
    f32x2 d;
    asm("v_pk_add_f32 %0, %1, %2" : "=v"(d) : "v"(a), "v"(b));
    return d;
}
__device__ __forceinline__ f32x2 pk_fma(f32x2 a, f32x2 b, f32x2 c) {
    f32x2 d;
    asm("v_pk_fma_f32 %0, %1, %2, %3" : "=v"(d) : "v"(a), "v"(b), "v"(c));
    return d;
}

// ---------------------------------------------------------------------------
// Prepass A: split A*4096 into fp16 hi/lo, GEMM-tile-ready swizzled layout.
// ---------------------------------------------------------------------------
__global__ __launch_bounds__(256) void splitA_kernel(
    const float* __restrict__ A, _Float16* __restrict__ Ath, _Float16* __restrict__ Atl)
{
    const int g   = blockIdx.x * 256 + threadIdx.x;   // 8192*96 total
    const int row = g / 96;
    const int o   = g - row * 96;      // k-octet 0..95
    const int ks  = o >> 2, qq = o & 3;
    const int r   = row & 127, rb = row >> 7;
    const size_t dst = (size_t)(rb * 24 + ks) * 4096 + r * 32 + ((qq ^ ((r >> 1) & 3)) << 3);

    f32x4 v0 = *(const f32x4*)(A + (size_t)row * H_ + o * 8);
    f32x4 v1 = *(const f32x4*)(A + (size_t)row * H_ + o * 8 + 4);
    f16x8 hi, lo;
#pragma unroll
    for (int e = 0; e < 8; e++) {
        float x = ((e < 4) ? v0[e] : v1[e - 4]) * SCALE_UP;
        _Float16 h = (_Float16)x;
        hi[e] = h;
        lo[e] = (_Float16)(x - (float)h);
    }
    *(f16x8*)&Ath[dst] = hi;
    *(f16x8*)&Atl[dst] = lo;
}

// ---------------------------------------------------------------------------
// Prepass W: same split for W*4096 (transposed tile layout).
// ---------------------------------------------------------------------------
__global__ __launch_bounds__(256) void splitW_kernel(
    const float* __restrict__ W, _Float16* __restrict__ Wth, _Float16* __restrict__ Wtl)
{
    const int g   = blockIdx.x * 256 + threadIdx.x;   // 3072*96 total
    const int ko  = g / NK_;            // k-octet 0..95
    const int col = g - ko * NK_;
    const int k0  = ko * 8;
    const int cb  = col >> 7, n = col & 127;
    const int ks  = k0 >> 5, qq = (k0 & 31) >> 3;
    const size_t dst = (size_t)(cb * 24 + ks) * 4096 + n * 32 + ((qq ^ ((n >> 1) & 3)) << 3);

    f16x8 hi, lo;
#pragma unroll
    for (int j = 0; j < 8; j++) {
        float x = W[(size_t)(k0 + j) * NK_ + col] * SCALE_UP;
        _Float16 h = (_Float16)x;
        hi[j] = h;
        lo[j] = (_Float16)(x - (float)h);
    }
    *(f16x8*)&Wth[dst] = hi;
    *(f16x8*)&Wtl[dst] = lo;
}

// ---------------------------------------------------------------------------
// GEMM: em = sigmoid((Ah+Al)@(Wh+Wl)*2^-24 + bias) via fp16 MFMA (3 terms).
// Unchanged from R3 (known-good).
// ---------------------------------------------------------------------------
__global__ __launch_bounds__(256, 2) void gemm_mfma_sigmoid_kernel(
    const _Float16* __restrict__ Ath, const _Float16* __restrict__ Atl,
    const _Float16* __restrict__ Wth, const _Float16* __restrict__ Wtl,
    const float* __restrict__ bias, float* __restrict__ em)
{
    __shared__ _Float16 lds[2][4][4096];   // 64 KB

    const int tid  = threadIdx.x;
    const int cb   = blockIdx.x;
    const int rb   = blockIdx.y;
    const int lane = tid & 63;
    const int w    = tid >> 6;
    const int wr   = w >> 1, wc = w & 1;
    const int fr   = lane & 15;
    const int kg   = lane >> 4;

    const _Float16* srcs[4] = {
        Ath + (size_t)(rb * 24) * 4096, Atl + (size_t)(rb * 24) * 4096,
        Wth + (size_t)(cb * 24) * 4096, Wtl + (size_t)(cb * 24) * 4096 };

    auto stage = [&](int ks, int bb) {
#pragma unroll
        for (int m = 0; m < 4; m++) {
            const _Float16* s = srcs[m] + (size_t)ks * 4096 + w * 1024 + lane * 8;
            _Float16* d = &lds[bb][m][w * 1024];
            load_lds16(s, d);
            load_lds16(s + 512, d + 512);
        }
    };

    f32x4 acc[4][4];
#pragma unroll
    for (int i = 0; i < 4; i++)
#pragma unroll
        for (int j = 0; j < 4; j++) acc[i][j] = (f32x4)0.0f;

    int cur = 0;
    stage(0, 0);

    for (int ks = 0; ks < 24; ks++) {
        __syncthreads();
        if (ks + 1 < 24) stage(ks + 1, cur ^ 1);

        f16x8 fah[4], fal[4], fbh[4], fbl[4];
#pragma unroll
        for (int mi = 0; mi < 4; mi++) {
            const int r   = wr * 64 + mi * 16 + fr;
            const int idx = r * 32 + ((kg ^ ((r >> 1) & 3)) << 3);
            fah[mi] = *(const f16x8*)&lds[cur][0][idx];
            fal[mi] = *(const f16x8*)&lds[cur][1][idx];
        }
#pragma unroll
        for (int ni = 0; ni < 4; ni++) {
            const int r   = wc * 64 + ni * 16 + fr;
            const int idx = r * 32 + ((kg ^ ((r >> 1) & 3)) << 3);
            fbh[ni] = *(const f16x8*)&lds[cur][2][idx];
            fbl[ni] = *(const f16x8*)&lds[cur][3][idx];
        }
#pragma unroll
        for (int mi = 0; mi < 4; mi++)
#pragma unroll
            for (int ni = 0; ni < 4; ni++) {
                acc[mi][ni] = __builtin_amdgcn_mfma_f32_16x16x32_f16(fah[mi], fbh[ni], acc[mi][ni], 0, 0, 0);
                acc[mi][ni] = __builtin_amdgcn_mfma_f32_16x16x32_f16(fah[mi], fbl[ni], acc[mi][ni], 0, 0, 0);
                acc[mi][ni] = __builtin_amdgcn_mfma_f32_16x16x32_f16(fal[mi], fbh[ni], acc[mi][ni], 0, 0, 0);
            }
        cur ^= 1;
    }

    const int er = rb * 128 + wr * 64 + (lane >> 4) * 4;
    const int ec = cb * 128 + wc * 64 + fr;
#pragma unroll
    for (int ni = 0; ni < 4; ni++) {
        const int   gc = ec + ni * 16;
        const float bv = bias[gc];
#pragma unroll
        for (int mi = 0; mi < 4; mi++)
#pragma unroll
            for (int r = 0; r < 4; r++) {
                const int gr = er + mi * 16 + r;
                float x = acc[mi][ni][r] * SCALE_DOWN + bv;
                em[(size_t)gr * NK_ + gc] = 1.0f / (1.0f + __expf(-x));
            }
    }
}

// ---------------------------------------------------------------------------
// CRF forward + fused backtrace, v2.
//  - trans column + exp(column) in 64 VGPRs (t2/E2 pairs, const-indexed)
//  - exchange via split e_s/v_s arrays: 2x ds_write_b32 + 16x b128/step
//  - packed fp32 (v_pk_add/fma) inner loop; Viterbi fp32 adds bit-exact
//  - no per-step max: constant shift 4.0 + exact lane-0 renorm every 16
//  - gold score hoisted out of the loop (3 gathers/lane)
// ---------------------------------------------------------------------------
__global__ __launch_bounds__(256) void crf_scan_kernel(
    const float* __restrict__ em,       // [B_, NK_]
    const int* __restrict__ target,     // [B_, T_]
    const float* __restrict__ trans,    // [K_, K_]
    float* __restrict__ out_tags,       // [B_, T_] as f32
    float* __restrict__ ll)             // [B_]
{
    __shared__ float  trans_s[K_ * K_];          // 4 KB
    __shared__ float  e_s[8][K_];                // 1 KB
    __shared__ float  v_s[8][K_];                // 1 KB
    __shared__ unsigned int bp_s[8][24][K_];     // 24 KB
    __shared__ unsigned char tgt_s[8][T_];       // 768 B

    const int tid = threadIdx.x;
    const int g   = tid >> 5;
    const int k   = tid & 31;
    const int b   = blockIdx.x * 8 + g;

    for (int i = tid; i < K_ * K_; i += 256) trans_s[i] = trans[i];
    __syncthreads();

    // per-pair transition constants in registers (c = pair of prev-tags 2c,2c+1)
    f32x2 t2[16], E2[16];
#pragma unroll
    for (int c = 0; c < 16; c++) {
        float a0 = trans_s[(2 * c) * K_ + k];
        float a1 = trans_s[(2 * c + 1) * K_ + k];
        t2[c] = (f32x2){a0, a1};
        E2[c] = (f32x2){__expf(a0), __expf(a1)};
    }

    const float* emb = em + (size_t)b * NK_ + k;

    // ---- gold-path score, hoisted: lane k covers t in {k, k+32, k+64} ----
    const int tg0 = target[b * T_ + k];
    const int tg1 = target[b * T_ + 32 + k];
    const int tg2 = target[b * T_ + 64 + k];
    tgt_s[g][k] = (unsigned char)tg0;
    tgt_s[g][k + 32] = (unsigned char)tg1;
    tgt_s[g][k + 64] = (unsigned char)tg2;
    __builtin_amdgcn_wave_barrier();

    const float* emrow = em + (size_t)b * NK_;
    float sc = emrow[k * K_ + tg0] + emrow[(k + 32) * K_ + tg1] + emrow[(k + 64) * K_ + tg2];
    if (k > 0) sc += trans_s[(int)tgt_s[g][k - 1] * K_ + tg0];
    sc += trans_s[(int)tgt_s[g][k + 31] * K_ + tg1];
    sc += trans_s[(int)tgt_s[g][k + 63] * K_ + tg2];

    // ---- init ----
    const float em0 = emb[0];
    float beta = em0;     // shifted alpha
    float v    = em0;     // Viterbi score (exact fp32, matches np bitwise)
    float Cr   = 0.0f;    // accumulated renorm shifts
    unsigned int bpw = 0;

    float em_t = emb[1 * K_];   // prefetch t=1

    // one forward step; sh = (t-1)&3 as a compile-time constant
    auto STEP = [&](int t, int sh) {
        float em_n = emb[(t + 1) * K_];   // prefetch next (last one reads scratch; unused)
        float e = __expf(beta);
        e_s[g][k] = e;
        v_s[g][k] = v;
        __builtin_amdgcn_wave_barrier();

        f32x2 acc = (f32x2){0.0f, 0.0f};
        float bv = -1e30f;
        int   bi = 0;
#pragma unroll
        for (int q = 0; q < 8; q++) {
            f32x4 eq = *(const f32x4*)&e_s[g][q * 4];
            f32x4 vq = *(const f32x4*)&v_s[g][q * 4];
            acc = pk_fma((f32x2){eq.x, eq.y}, E2[2 * q], acc);
            acc = pk_fma((f32x2){eq.z, eq.w}, E2[2 * q + 1], acc);
            f32x2 svA = pk_add((f32x2){vq.x, vq.y}, t2[2 * q]);
            f32x2 svB = pk_add((f32x2){vq.z, vq.w}, t2[2 * q + 1]);
            // merge pair A (prev-tags 4q, 4q+1): tie -> lower index
            {
                float wv = (svA.y > svA.x) ? svA.y : svA.x;
                int   wi = (svA.y > svA.x) ? (4 * q + 1) : (4 * q);
                if (wv > bv) { bv = wv; bi = wi; }
            }
            // merge pair B (prev-tags 4q+2, 4q+3)
            {
                float wv = (svB.y > svB.x) ? svB.y : svB.x;
                int   wi = (svB.y > svB.x) ? (4 * q + 3) : (4 * q + 2);
                if (wv > bv) { bv = wv; bi = wi; }
            }
        }
        float sum = acc.x + acc.y;
        beta = __logf(sum) + (em_t - 4.0f);
        v    = bv + em_t;
        bpw |= (unsigned int)bi << (8 * sh);
        if (sh == 3) { bp_s[g][(t - 1) >> 2][k] = bpw; bpw = 0; }
        em_t = em_n;
    };

    for (int tb = 1; tb <= 89; tb += 4) {
        STEP(tb, 0); STEP(tb + 1, 1); STEP(tb + 2, 2); STEP(tb + 3, 3);
        if ((tb & 15) == 13) {           // after t = 16,32,48,64,80: exact renorm
            float d = __shfl(beta, 0, 32);
            beta -= d;
            Cr += d;
        }
    }
    STEP(93, 0); STEP(94, 1); STEP(95, 2);
    bp_s[g][23][k] = bpw;
    __builtin_amdgcn_wave_barrier();

    // ---- group reductions ----
    float m2 = beta;
#pragma unroll
    for (int d = 16; d >= 1; d >>= 1) m2 = fmaxf(m2, __shfl_xor(m2, d));
    float s2 = __expf(beta - m2);
#pragma unroll
    for (int d = 16; d >= 1; d >>= 1) s2 += __shfl_xor(s2, d);
    const float logZ = 380.0f + Cr + m2 + __logf(s2);   // 380 = 4.0 * 95 const shifts

    float scr = sc;
#pragma unroll
    for (int d = 16; d >= 1; d >>= 1) scr += __shfl_xor(scr, d);

    float bvv = v;
    int   bii = k;
#pragma unroll
    for (int d = 16; d >= 1; d >>= 1) {
        float ov = __shfl_xor(bvv, d);
        int   oi = __shfl_xor(bii, d);
        if (ov > bvv || (ov == bvv && oi < bii)) { bvv = ov; bii = oi; }
    }

    if (k == 0) {
        ll[b] = scr - logZ;
        float* ot = out_tags + (size_t)b * T_;
        int tag = bii;
        ot[T_ - 1] = (float)tag;
        for (int t = T_ - 2; t >= 0; t--) {
            unsigned int wd = bp_s[g][t >> 2][tag];
            tag = (wd >> (8 * (t & 3))) & 0xFF;
            ot[t] = (float)tag;
        }
    }
}

// ---------------------------------------------------------------------------
extern "C" void kernel_launch(void* const* d_in, const int* in_sizes, int n_in,
                              void* d_out, int out_size, void* d_ws, size_t ws_size,
                              hipStream_t stream)
{
    const float* hidden = (const float*)d_in[0];
    const int*   target = (const int*)d_in[1];
    const float* W      = (const float*)d_in[2];
    const float* bias   = (const float*)d_in[3];
    const float* trans  = (const float*)d_in[4];

    float* out      = (float*)d_out;
    float* out_tags = out;                    // B_*T_ tags (as f32)
    float* out_ll   = out + (size_t)B_ * T_;  // B_ log-likelihoods

    char* ws = (char*)d_ws;
    const size_t emB = (size_t)B_ * NK_ * 4;   // 100.66 MB
    const size_t ahB = (size_t)B_ * H_ * 2;    // 12.58 MB
    const size_t whB = (size_t)H_ * NK_ * 2;   // 4.72 MB
    float*    em  = (float*)ws;
    _Float16* Ath = (_Float16*)(ws + emB);
    _Float16* Atl = (_Float16*)(ws + emB + ahB);
    _Float16* Wth = (_Float16*)(ws + emB + 2 * ahB);
    _Float16* Wtl = (_Float16*)(ws + emB + 2 * ahB + whB);

    splitA_kernel<<<(B_ * 96) / 256, 256, 0, stream>>>(hidden, Ath, Atl);
    splitW_kernel<<<(NK_ * 96) / 256, 256, 0, stream>>>(W, Wth, Wtl);

    dim3 gemm_grid(NK_ / 128, B_ / 128);  // (24, 64)
    gemm_mfma_sigmoid_kernel<<<gemm_grid, 256, 0, stream>>>(Ath, Atl, Wth, Wtl, bias, em);

    crf_scan_kernel<<<B_ / 8, 256, 0, stream>>>(em, target, trans, out_tags, out_ll);
}